// Round 3
// baseline (536.175 us; speedup 1.0000x reference)
//
#include <hip/hip_runtime.h>

#define BATCH 50
#define NATOMS 512
#define NBONDS 4096
#define BLK 1024

__device__ __forceinline__ float sigmoidf_(float x){ return 1.f/(1.f+__expf(-x)); }

// exact transcription of reference _taper
__device__ __forceinline__ float taperf_(float r, float rmin, float rmax){
    float r3  = (r > rmax) ? 1.f : 0.f;
    bool  ok  = (r <= rmax) && (r > rmin);
    float r2  = ok ? r   : 0.f;
    float r20 = ok ? 1.f : 0.f;
    float d   = rmin - rmax;
    float rterm = 1.f/(d*d*d);
    float rm  = rmin*r20;
    float rd  = rm - r2;
    float trm1 = rm + 2.f*r2 - 3.f*rmax*r20;
    return rterm*rd*rd*trm1 + r3;
}

// One block per batch element. Everything fused; no global intermediates.
__global__ __launch_bounds__(BLK) void fused_kernel(
    const float* __restrict__ x, const float* __restrict__ cell, const float* __restrict__ rcell,
    const float* __restrict__ sp_p, const float* __restrict__ gp, const float* __restrict__ bp,
    const float* __restrict__ fe_wi, const float* __restrict__ fe_w, const float* __restrict__ fe_b,
    const float* __restrict__ fe_wo, const float* __restrict__ fe_bo,
    const int* __restrict__ bdid, const int* __restrict__ spec,
    float* __restrict__ out)
{
    __shared__ unsigned bitT[NATOMS*NATOMS/32];              // 32 KiB dedup bit-table
    __shared__ float sD[NATOMS], sDpi[NATOMS], sSO[NATOMS];  // per-atom accumulators
    __shared__ float sx[NATOMS*3];                           // this batch's coords
    __shared__ __align__(16) float s_wi[24];
    __shared__ __align__(16) float s_w[320];
    __shared__ __align__(16) float s_bb[40];
    __shared__ __align__(16) float s_wo[8];
    __shared__ float s_part[BLK/64];

    int tid = threadIdx.x;
    int b   = blockIdx.x;

    // ---- stage LDS ----
    for(int t=tid;t<NATOMS*NATOMS/32;t+=BLK) bitT[t]=0u;
    if(tid < NATOMS){ sD[tid]=0.f; sDpi[tid]=0.f; sSO[tid]=0.f; }
    for(int t=tid;t<NATOMS*3;t+=BLK) sx[t]=x[(size_t)b*NATOMS*3 + t];
    for(int t=tid;t<24;t+=BLK)  s_wi[t]=fe_wi[t];
    for(int t=tid;t<320;t+=BLK) s_w[t]=fe_w[t];
    for(int t=tid;t<40;t+=BLK)  s_bb[t]=fe_b[t];
    for(int t=tid;t<8;t+=BLK)   s_wo[t]=fe_wo[t];

    float c0=cell[b*9+0],c1=cell[b*9+1],c2=cell[b*9+2],
          c3=cell[b*9+3],c4=cell[b*9+4],c5=cell[b*9+5],
          c6=cell[b*9+6],c7=cell[b*9+7],c8=cell[b*9+8];
    float rc0=rcell[b*9+0],rc1=rcell[b*9+1],rc2=rcell[b*9+2],
          rc3=rcell[b*9+3],rc4=rcell[b*9+4],rc5=rcell[b*9+5],
          rc6=rcell[b*9+6],rc7=rcell[b*9+7],rc8=rcell[b*9+8];

    float botol = gp[6];
    float rosi=bp[0], ropi=bp[1], ropp=bp[2];
    float bo1=bp[3], bo2=bp[4], bo3=bp[5], bo4=bp[6], bo5=bp[7], bo6=bp[8], Desi=bp[9];
    float bo_out = fe_bo[0];
    float tmax = 2.f*botol;

    __syncthreads();

    // ---- bond phase: 4 bonds per thread ----
    float eb = 0.f;
    #pragma unroll
    for(int c=0;c<NBONDS/BLK;c++){
        int k = c*BLK + tid;
        int i = bdid[2*k], j = bdid[2*k+1];
        float dx0 = sx[3*i+0]-sx[3*j+0];
        float dx1 = sx[3*i+1]-sx[3*j+1];
        float dx2 = sx[3*i+2]-sx[3*j+2];
        float f0 = dx0*rc0+dx1*rc3+dx2*rc6;
        float f1 = dx0*rc1+dx1*rc4+dx2*rc7;
        float f2 = dx0*rc2+dx1*rc5+dx2*rc8;
        f0 = (f0>0.5f)?f0-1.f:f0; f0 = (f0<-0.5f)?f0+1.f:f0;
        f1 = (f1>0.5f)?f1-1.f:f1; f1 = (f1<-0.5f)?f1+1.f:f1;
        f2 = (f2>0.5f)?f2-1.f:f2; f2 = (f2<-0.5f)?f2+1.f:f2;
        float v0 = f0*c0+f1*c3+f2*c6;
        float v1 = f0*c1+f1*c4+f2*c7;
        float v2 = f0*c2+f1*c5+f2*c8;
        float r = sqrtf(v0*v0+v1*v1+v2*v2);

        float eterm1 = (1.f+botol)*__expf(bo1*__powf(r/rosi, bo2));
        float eterm2 = __expf(bo3*__powf(r/ropi, bo4));
        float eterm3 = __expf(bo5*__powf(r/ropp, bo6));
        float si = taperf_(eterm1, botol, tmax)*(eterm1-botol);
        float pi = taperf_(eterm2, botol, tmax)*eterm2;
        float pp = taperf_(eterm3, botol, tmax)*eterm3;

        // MLP: 3 -> 8 -> (8x8)x5 -> 1, sigmoid everywhere
        float o[8];
        #pragma unroll
        for(int u=0;u<8;u++)
            o[u] = sigmoidf_(si*s_wi[u] + pi*s_wi[8+u] + pp*s_wi[16+u]);
        #pragma unroll
        for(int l=0;l<5;l++){
            float a[8];
            float4 bb0 = ((const float4*)(s_bb + l*8))[0];
            float4 bb1 = ((const float4*)(s_bb + l*8))[1];
            a[0]=bb0.x; a[1]=bb0.y; a[2]=bb0.z; a[3]=bb0.w;
            a[4]=bb1.x; a[5]=bb1.y; a[6]=bb1.z; a[7]=bb1.w;
            #pragma unroll
            for(int v=0;v<8;v++){
                const float4* wrow = (const float4*)(s_w + (l*8+v)*8);
                float4 w0 = wrow[0], w1 = wrow[1];
                float ov = o[v];
                a[0]=fmaf(ov,w0.x,a[0]); a[1]=fmaf(ov,w0.y,a[1]);
                a[2]=fmaf(ov,w0.z,a[2]); a[3]=fmaf(ov,w0.w,a[3]);
                a[4]=fmaf(ov,w1.x,a[4]); a[5]=fmaf(ov,w1.y,a[5]);
                a[6]=fmaf(ov,w1.z,a[6]); a[7]=fmaf(ov,w1.w,a[7]);
            }
            #pragma unroll
            for(int u=0;u<8;u++) o[u]=sigmoidf_(a[u]);
        }
        float4 wo0 = ((const float4*)s_wo)[0];
        float4 wo1 = ((const float4*)s_wo)[1];
        float acc = bo_out;
        acc = fmaf(o[0],wo0.x,acc); acc = fmaf(o[1],wo0.y,acc);
        acc = fmaf(o[2],wo0.z,acc); acc = fmaf(o[3],wo0.w,acc);
        acc = fmaf(o[4],wo1.x,acc); acc = fmaf(o[5],wo1.y,acc);
        acc = fmaf(o[6],wo1.z,acc); acc = fmaf(o[7],wo1.w,acc);
        eb += -Desi*sigmoidf_(acc);              // all bonds, duplicates included

        // dedup: first thread to set bit (i,j) owns the pair ('.set' semantics;
        // duplicates carry identical values so any winner is correct)
        unsigned pos = (unsigned)i*NATOMS + (unsigned)j;
        unsigned m = 1u << (pos & 31u);
        unsigned old = atomicOr(&bitT[pos>>5], m);
        if(!(old & m)){
            float bop = si+pi+pp, dpi = pi+pp;
            atomicAdd(&sD[i], bop);  atomicAdd(&sD[j], bop);
            atomicAdd(&sDpi[i], dpi); atomicAdd(&sDpi[j], dpi);
            atomicAdd(&sSO[i], si);  atomicAdd(&sSO[j], si);
        }
    }
    __syncthreads();

    // ---- atom phase: threads 0..511 ----
    float ea = 0.f;
    if(tid < NATOMS){
        float lp1=gp[0], ovun3=gp[1], ovun4=gp[2], ovun6=gp[3], ovun7=gp[4], ovun8=gp[5];
        int s = spec[tid];
        float val  = sp_p[s*5+0], vale = sp_p[s*5+1], lp2 = sp_p[s*5+2];
        float ovun2= sp_p[s*5+3], ovun5= sp_p[s*5+4];
        float D = sD[tid], Dpi = sDpi[tid], so = sSO[tid];

        float Nlp = 0.5f*(vale-val);
        float de  = 0.5f*(D-vale);
        float De  = fminf(ceilf(de), 0.f);       // -relu(-ceil(x)) == min(ceil(x),0)
        float t   = 1.f + de - De;
        float nlp = -De + __expf(-lp1*4.f*t*t);
        float Dlp = fmaxf(Nlp - nlp + 1.f, 0.f) - 1.f;
        float Elone = lp2*Dlp/(1.f+__expf(-75.f*Dlp));
        float dlp = D - val - Dlp/(1.f + ovun3*__expf(ovun4*Dpi));
        float denom = dlp + val;
        float otrm1 = 1.f/((denom!=0.f)?denom:1e-8f);
        float Eover = so*otrm1*dlp*sigmoidf_(-ovun2*dlp);
        float Eunder = -ovun5*(1.f-__expf(ovun6*dlp))*sigmoidf_(ovun2*dlp)
                       /(1.f + ovun7*__expf(ovun8*Dpi));
        ea = Elone + Eover + Eunder;
    }

    // ---- block reduction, single store ----
    float tot = eb + ea;
    #pragma unroll
    for(int off=32;off>0;off>>=1) tot += __shfl_down(tot, off, 64);
    if((tid & 63)==0) s_part[tid>>6] = tot;
    __syncthreads();
    if(tid < BLK/64){
        float v = s_part[tid];
        #pragma unroll
        for(int off=BLK/128; off>0; off>>=1) v += __shfl_down(v, off, 64);
        if(tid==0) out[b] = v;
    }
}

extern "C" void kernel_launch(void* const* d_in, const int* in_sizes, int n_in,
                              void* d_out, int out_size, void* d_ws, size_t ws_size,
                              hipStream_t stream)
{
    const float* x     = (const float*)d_in[0];
    const float* cell  = (const float*)d_in[1];
    const float* rcell = (const float*)d_in[2];
    const float* sp_p  = (const float*)d_in[3];
    const float* gp    = (const float*)d_in[4];
    const float* bp    = (const float*)d_in[5];
    const float* fe_wi = (const float*)d_in[6];
    const float* fe_w  = (const float*)d_in[7];
    const float* fe_b  = (const float*)d_in[8];
    const float* fe_wo = (const float*)d_in[9];
    const float* fe_bo = (const float*)d_in[10];
    const int*   bdid  = (const int*)d_in[11];
    const int*   spec  = (const int*)d_in[12];
    float* out = (float*)d_out;

    fused_kernel<<<dim3(BATCH), BLK, 0, stream>>>(
        x, cell, rcell, sp_p, gp, bp, fe_wi, fe_w, fe_b, fe_wo, fe_bo, bdid, spec, out);
}

// Round 4
// 237.716 us; speedup vs baseline: 2.2555x; 2.2555x over previous
//
#include <hip/hip_runtime.h>

#define BATCH 50
#define NATOMS 512
#define NBONDS 4096
#define CH 4                    // bond chunks per batch
#define CHB (NBONDS/CH)         // 1024 bonds per block
#define BBLK 512                // bond-kernel block size

__device__ __forceinline__ float sigmoidf_(float x){ return 1.f/(1.f+__expf(-x)); }

// exact transcription of reference _taper
__device__ __forceinline__ float taperf_(float r, float rmin, float rmax){
    float r3  = (r > rmax) ? 1.f : 0.f;
    bool  ok  = (r <= rmax) && (r > rmin);
    float r2  = ok ? r   : 0.f;
    float r20 = ok ? 1.f : 0.f;
    float d   = rmin - rmax;
    float rterm = 1.f/(d*d*d);
    float rm  = rmin*r20;
    float rd  = rm - r2;
    float trm1 = rm + 2.f*r2 - 3.f*rmax*r20;
    return rterm*rd*rd*trm1 + r3;
}

// Single block: init used table entries, then claim (lowest bond idx owns pair).
// Single-block => __syncthreads orders init before atomicMin. Also zeroes out.
__global__ __launch_bounds__(1024) void setup_kernel(const int* __restrict__ bdid,
                                                     unsigned* __restrict__ table,
                                                     float* __restrict__ out){
    int tid = threadIdx.x;
    if(tid < BATCH) out[tid] = 0.f;
    #pragma unroll
    for(int t=tid;t<NBONDS;t+=1024){
        int i = bdid[2*t], j = bdid[2*t+1];
        table[i*NATOMS + j] = 0xFFFFFFFFu;
    }
    __syncthreads();
    #pragma unroll
    for(int t=tid;t<NBONDS;t+=1024){
        int i = bdid[2*t], j = bdid[2*t+1];
        atomicMin(&table[i*NATOMS + j], (unsigned)t);
    }
}

// grid (CH, BATCH), 512 threads. 2 bonds/thread. LDS per-atom partials,
// non-atomic partial writes to ws; ebond via wave reduce + atomicAdd.
__global__ __launch_bounds__(BBLK, 2) void bond_kernel(
    const float* __restrict__ x, const float* __restrict__ cell, const float* __restrict__ rcell,
    const float* __restrict__ gp, const float* __restrict__ bp,
    const float* __restrict__ fe_wi, const float* __restrict__ fe_w, const float* __restrict__ fe_b,
    const float* __restrict__ fe_wo, const float* __restrict__ fe_bo,
    const int* __restrict__ bdid, const unsigned* __restrict__ table,
    float* __restrict__ part,      // [CH][BATCH][3*NATOMS]
    float* __restrict__ out)
{
    __shared__ float sx[NATOMS*3];
    __shared__ float sAcc[3*NATOMS];            // [0:512)=D, [512:1024)=Dpi, [1024:1536)=SO
    __shared__ __align__(16) float s_wi[24];
    __shared__ __align__(16) float s_w[320];
    __shared__ __align__(16) float s_bb[40];
    __shared__ __align__(16) float s_wo[8];

    int tid = threadIdx.x;
    int c   = blockIdx.x;
    int b   = blockIdx.y;

    for(int t=tid;t<NATOMS*3;t+=BBLK){ sx[t]=x[(size_t)b*NATOMS*3 + t]; sAcc[t]=0.f; }
    for(int t=tid;t<24;t+=BBLK)  s_wi[t]=fe_wi[t];
    for(int t=tid;t<320;t+=BBLK) s_w[t]=fe_w[t];
    for(int t=tid;t<40;t+=BBLK)  s_bb[t]=fe_b[t];
    for(int t=tid;t<8;t+=BBLK)   s_wo[t]=fe_wo[t];

    float c0=cell[b*9+0],c1=cell[b*9+1],c2=cell[b*9+2],
          c3=cell[b*9+3],c4=cell[b*9+4],c5=cell[b*9+5],
          c6=cell[b*9+6],c7=cell[b*9+7],c8=cell[b*9+8];
    float rc0=rcell[b*9+0],rc1=rcell[b*9+1],rc2=rcell[b*9+2],
          rc3=rcell[b*9+3],rc4=rcell[b*9+4],rc5=rcell[b*9+5],
          rc6=rcell[b*9+6],rc7=rcell[b*9+7],rc8=rcell[b*9+8];

    float botol = gp[6];
    float rosi=bp[0], ropi=bp[1], ropp=bp[2];
    float bo1=bp[3], bo2=bp[4], bo3=bp[5], bo4=bp[6], bo5=bp[7], bo6=bp[8], Desi=bp[9];
    float bo_out = fe_bo[0];
    float tmax = 2.f*botol;

    __syncthreads();

    float eb = 0.f;
    #pragma unroll
    for(int q=0;q<CHB/BBLK;q++){
        int k = c*CHB + q*BBLK + tid;
        int i = bdid[2*k], j = bdid[2*k+1];
        float dx0 = sx[3*i+0]-sx[3*j+0];
        float dx1 = sx[3*i+1]-sx[3*j+1];
        float dx2 = sx[3*i+2]-sx[3*j+2];
        float f0 = dx0*rc0+dx1*rc3+dx2*rc6;
        float f1 = dx0*rc1+dx1*rc4+dx2*rc7;
        float f2 = dx0*rc2+dx1*rc5+dx2*rc8;
        f0 = (f0>0.5f)?f0-1.f:f0; f0 = (f0<-0.5f)?f0+1.f:f0;
        f1 = (f1>0.5f)?f1-1.f:f1; f1 = (f1<-0.5f)?f1+1.f:f1;
        f2 = (f2>0.5f)?f2-1.f:f2; f2 = (f2<-0.5f)?f2+1.f:f2;
        float v0 = f0*c0+f1*c3+f2*c6;
        float v1 = f0*c1+f1*c4+f2*c7;
        float v2 = f0*c2+f1*c5+f2*c8;
        float r = sqrtf(v0*v0+v1*v1+v2*v2);

        float eterm1 = (1.f+botol)*__expf(bo1*__powf(r/rosi, bo2));
        float eterm2 = __expf(bo3*__powf(r/ropi, bo4));
        float eterm3 = __expf(bo5*__powf(r/ropp, bo6));
        float si = taperf_(eterm1, botol, tmax)*(eterm1-botol);
        float pi = taperf_(eterm2, botol, tmax)*eterm2;
        float pp = taperf_(eterm3, botol, tmax)*eterm3;

        // MLP: 3 -> 8 -> (8x8)x5 -> 1, sigmoid everywhere
        float o[8];
        #pragma unroll
        for(int u=0;u<8;u++)
            o[u] = sigmoidf_(si*s_wi[u] + pi*s_wi[8+u] + pp*s_wi[16+u]);
        #pragma unroll
        for(int l=0;l<5;l++){
            float a[8];
            float4 bb0 = ((const float4*)(s_bb + l*8))[0];
            float4 bb1 = ((const float4*)(s_bb + l*8))[1];
            a[0]=bb0.x; a[1]=bb0.y; a[2]=bb0.z; a[3]=bb0.w;
            a[4]=bb1.x; a[5]=bb1.y; a[6]=bb1.z; a[7]=bb1.w;
            #pragma unroll
            for(int v=0;v<8;v++){
                const float4* wrow = (const float4*)(s_w + (l*8+v)*8);
                float4 w0 = wrow[0], w1 = wrow[1];
                float ov = o[v];
                a[0]=fmaf(ov,w0.x,a[0]); a[1]=fmaf(ov,w0.y,a[1]);
                a[2]=fmaf(ov,w0.z,a[2]); a[3]=fmaf(ov,w0.w,a[3]);
                a[4]=fmaf(ov,w1.x,a[4]); a[5]=fmaf(ov,w1.y,a[5]);
                a[6]=fmaf(ov,w1.z,a[6]); a[7]=fmaf(ov,w1.w,a[7]);
            }
            #pragma unroll
            for(int u=0;u<8;u++) o[u]=sigmoidf_(a[u]);
        }
        float4 wo0 = ((const float4*)s_wo)[0];
        float4 wo1 = ((const float4*)s_wo)[1];
        float acc = bo_out;
        acc = fmaf(o[0],wo0.x,acc); acc = fmaf(o[1],wo0.y,acc);
        acc = fmaf(o[2],wo0.z,acc); acc = fmaf(o[3],wo0.w,acc);
        acc = fmaf(o[4],wo1.x,acc); acc = fmaf(o[5],wo1.y,acc);
        acc = fmaf(o[6],wo1.z,acc); acc = fmaf(o[7],wo1.w,acc);
        eb += -Desi*sigmoidf_(acc);             // all bonds, duplicates included

        // per-atom scatter, owned (unique) pairs only — LDS atomics
        if(table[i*NATOMS + j] == (unsigned)k){
            float bop = si+pi+pp, dpi = pi+pp;
            atomicAdd(&sAcc[i],            bop); atomicAdd(&sAcc[j],            bop);
            atomicAdd(&sAcc[NATOMS+i],     dpi); atomicAdd(&sAcc[NATOMS+j],     dpi);
            atomicAdd(&sAcc[2*NATOMS+i],   si ); atomicAdd(&sAcc[2*NATOMS+j],   si );
        }
    }
    __syncthreads();

    // non-atomic partial dump (6 KB, coalesced)
    float* pb = part + ((size_t)c*BATCH + b)*(3*NATOMS);
    for(int t=tid;t<3*NATOMS;t+=BBLK) pb[t] = sAcc[t];

    // ebond: one atomic per wave
    #pragma unroll
    for(int off=32;off>0;off>>=1) eb += __shfl_down(eb, off, 64);
    if((tid & 63)==0) atomicAdd(&out[b], eb);
}

// grid (BATCH), 512 threads: one atom each. Sum CH partials, atom formula.
__global__ __launch_bounds__(NATOMS) void atom_kernel(
    const float* __restrict__ sp_p, const float* __restrict__ gp, const int* __restrict__ spec,
    const float* __restrict__ part,
    float* __restrict__ out)
{
    int n = threadIdx.x;
    int b = blockIdx.x;

    float D = 0.f, Dpi = 0.f, so = 0.f;
    #pragma unroll
    for(int c=0;c<CH;c++){
        const float* pb = part + ((size_t)c*BATCH + b)*(3*NATOMS);
        D   += pb[n];
        Dpi += pb[NATOMS + n];
        so  += pb[2*NATOMS + n];
    }

    float lp1=gp[0], ovun3=gp[1], ovun4=gp[2], ovun6=gp[3], ovun7=gp[4], ovun8=gp[5];
    int s = spec[n];
    float val  = sp_p[s*5+0], vale = sp_p[s*5+1], lp2 = sp_p[s*5+2];
    float ovun2= sp_p[s*5+3], ovun5= sp_p[s*5+4];

    float Nlp = 0.5f*(vale-val);
    float de  = 0.5f*(D-vale);
    float De  = fminf(ceilf(de), 0.f);          // -relu(-ceil(x)) == min(ceil(x),0)
    float t   = 1.f + de - De;
    float nlp = -De + __expf(-lp1*4.f*t*t);
    float Dlp = fmaxf(Nlp - nlp + 1.f, 0.f) - 1.f;
    float Elone = lp2*Dlp/(1.f+__expf(-75.f*Dlp));
    float dlp = D - val - Dlp/(1.f + ovun3*__expf(ovun4*Dpi));
    float denom = dlp + val;
    float otrm1 = 1.f/((denom!=0.f)?denom:1e-8f);
    float Eover = so*otrm1*dlp*sigmoidf_(-ovun2*dlp);
    float Eunder = -ovun5*(1.f-__expf(ovun6*dlp))*sigmoidf_(ovun2*dlp)
                   /(1.f + ovun7*__expf(ovun8*Dpi));

    float e = Elone + Eover + Eunder;
    #pragma unroll
    for(int off=32;off>0;off>>=1) e += __shfl_down(e, off, 64);
    if((n & 63)==0) atomicAdd(&out[b], e);
}

extern "C" void kernel_launch(void* const* d_in, const int* in_sizes, int n_in,
                              void* d_out, int out_size, void* d_ws, size_t ws_size,
                              hipStream_t stream)
{
    const float* x     = (const float*)d_in[0];
    const float* cell  = (const float*)d_in[1];
    const float* rcell = (const float*)d_in[2];
    const float* sp_p  = (const float*)d_in[3];
    const float* gp    = (const float*)d_in[4];
    const float* bp    = (const float*)d_in[5];
    const float* fe_wi = (const float*)d_in[6];
    const float* fe_w  = (const float*)d_in[7];
    const float* fe_b  = (const float*)d_in[8];
    const float* fe_wo = (const float*)d_in[9];
    const float* fe_bo = (const float*)d_in[10];
    const int*   bdid  = (const int*)d_in[11];
    const int*   spec  = (const int*)d_in[12];
    float* out = (float*)d_out;

    // ws: claim table (1 MiB) | partials (CH*BATCH*1536 floats = 1.2 MiB)
    unsigned* table = (unsigned*)d_ws;
    float*    part  = (float*)(table + NATOMS*NATOMS);

    setup_kernel<<<1, 1024, 0, stream>>>(bdid, table, out);
    bond_kernel <<<dim3(CH, BATCH), BBLK, 0, stream>>>(
        x, cell, rcell, gp, bp, fe_wi, fe_w, fe_b, fe_wo, fe_bo, bdid, table, part, out);
    atom_kernel <<<BATCH, NATOMS, 0, stream>>>(sp_p, gp, spec, part, out);
}

// Round 5
// 187.886 us; speedup vs baseline: 2.8537x; 1.2652x over previous
//
#include <hip/hip_runtime.h>

#define BATCH 50
#define NATOMS 512
#define NBONDS 4096
#define CH 8                    // bond chunks per batch
#define CHB (NBONDS/CH)         // 512 bonds per block
#define BBLK 256                // bond-kernel block size

__device__ __forceinline__ float sigmoidf_(float x){ return 1.f/(1.f+__expf(-x)); }

// exact transcription of reference _taper
__device__ __forceinline__ float taperf_(float r, float rmin, float rmax){
    float r3  = (r > rmax) ? 1.f : 0.f;
    bool  ok  = (r <= rmax) && (r > rmin);
    float r2  = ok ? r   : 0.f;
    float r20 = ok ? 1.f : 0.f;
    float d   = rmin - rmax;
    float rterm = 1.f/(d*d*d);
    float rm  = rmin*r20;
    float rd  = rm - r2;
    float trm1 = rm + 2.f*r2 - 3.f*rmax*r20;
    return rterm*rd*rd*trm1 + r3;
}

// Single block: init used table entries, then claim (lowest bond idx owns pair).
// Single-block => __syncthreads orders init before atomicMin. Also zeroes out.
__global__ __launch_bounds__(1024) void setup_kernel(const int* __restrict__ bdid,
                                                     unsigned* __restrict__ table,
                                                     float* __restrict__ out){
    int tid = threadIdx.x;
    if(tid < BATCH) out[tid] = 0.f;
    #pragma unroll
    for(int t=tid;t<NBONDS;t+=1024){
        int i = bdid[2*t], j = bdid[2*t+1];
        table[i*NATOMS + j] = 0xFFFFFFFFu;
    }
    __syncthreads();
    #pragma unroll
    for(int t=tid;t<NBONDS;t+=1024){
        int i = bdid[2*t], j = bdid[2*t+1];
        atomicMin(&table[i*NATOMS + j], (unsigned)t);
    }
}

// grid (CH, BATCH), 256 threads, 2 bonds/thread. Plain __launch_bounds__(256):
// proven VGPR=204 no-spill config (R1). DO NOT add a min-waves arg — 128-VGPR
// caps spill ~1.6 KB/bond to scratch (R3: 64 VGPR @1024thr, R4: 128 @512thr,2).
__global__ __launch_bounds__(BBLK) void bond_kernel(
    const float* __restrict__ x, const float* __restrict__ cell, const float* __restrict__ rcell,
    const float* __restrict__ gp, const float* __restrict__ bp,
    const float* __restrict__ fe_wi, const float* __restrict__ fe_w, const float* __restrict__ fe_b,
    const float* __restrict__ fe_wo, const float* __restrict__ fe_bo,
    const int* __restrict__ bdid, const unsigned* __restrict__ table,
    float* __restrict__ part,      // [CH][BATCH][3*NATOMS]
    float* __restrict__ out)
{
    __shared__ float sx[NATOMS*3];
    __shared__ float sAcc[3*NATOMS];            // [0:512)=D, [512:1024)=Dpi, [1024:1536)=SO
    __shared__ __align__(16) float s_wi[24];
    __shared__ __align__(16) float s_w[320];
    __shared__ __align__(16) float s_bb[40];
    __shared__ __align__(16) float s_wo[8];

    int tid = threadIdx.x;
    int c   = blockIdx.x;
    int b   = blockIdx.y;

    for(int t=tid;t<NATOMS*3;t+=BBLK){ sx[t]=x[(size_t)b*NATOMS*3 + t]; sAcc[t]=0.f; }
    for(int t=tid;t<24;t+=BBLK)  s_wi[t]=fe_wi[t];
    for(int t=tid;t<320;t+=BBLK) s_w[t]=fe_w[t];
    for(int t=tid;t<40;t+=BBLK)  s_bb[t]=fe_b[t];
    for(int t=tid;t<8;t+=BBLK)   s_wo[t]=fe_wo[t];

    float c0=cell[b*9+0],c1=cell[b*9+1],c2=cell[b*9+2],
          c3=cell[b*9+3],c4=cell[b*9+4],c5=cell[b*9+5],
          c6=cell[b*9+6],c7=cell[b*9+7],c8=cell[b*9+8];
    float rc0=rcell[b*9+0],rc1=rcell[b*9+1],rc2=rcell[b*9+2],
          rc3=rcell[b*9+3],rc4=rcell[b*9+4],rc5=rcell[b*9+5],
          rc6=rcell[b*9+6],rc7=rcell[b*9+7],rc8=rcell[b*9+8];

    float botol = gp[6];
    float rosi=bp[0], ropi=bp[1], ropp=bp[2];
    float bo1=bp[3], bo2=bp[4], bo3=bp[5], bo4=bp[6], bo5=bp[7], bo6=bp[8], Desi=bp[9];
    float bo_out = fe_bo[0];
    float tmax = 2.f*botol;

    __syncthreads();

    float eb = 0.f;
    #pragma unroll
    for(int q=0;q<CHB/BBLK;q++){
        int k = c*CHB + q*BBLK + tid;
        int i = bdid[2*k], j = bdid[2*k+1];
        float dx0 = sx[3*i+0]-sx[3*j+0];
        float dx1 = sx[3*i+1]-sx[3*j+1];
        float dx2 = sx[3*i+2]-sx[3*j+2];
        float f0 = dx0*rc0+dx1*rc3+dx2*rc6;
        float f1 = dx0*rc1+dx1*rc4+dx2*rc7;
        float f2 = dx0*rc2+dx1*rc5+dx2*rc8;
        f0 = (f0>0.5f)?f0-1.f:f0; f0 = (f0<-0.5f)?f0+1.f:f0;
        f1 = (f1>0.5f)?f1-1.f:f1; f1 = (f1<-0.5f)?f1+1.f:f1;
        f2 = (f2>0.5f)?f2-1.f:f2; f2 = (f2<-0.5f)?f2+1.f:f2;
        float v0 = f0*c0+f1*c3+f2*c6;
        float v1 = f0*c1+f1*c4+f2*c7;
        float v2 = f0*c2+f1*c5+f2*c8;
        float r = sqrtf(v0*v0+v1*v1+v2*v2);

        float eterm1 = (1.f+botol)*__expf(bo1*__powf(r/rosi, bo2));
        float eterm2 = __expf(bo3*__powf(r/ropi, bo4));
        float eterm3 = __expf(bo5*__powf(r/ropp, bo6));
        float si = taperf_(eterm1, botol, tmax)*(eterm1-botol);
        float pi = taperf_(eterm2, botol, tmax)*eterm2;
        float pp = taperf_(eterm3, botol, tmax)*eterm3;

        // MLP: 3 -> 8 -> (8x8)x5 -> 1, sigmoid everywhere
        float o[8];
        #pragma unroll
        for(int u=0;u<8;u++)
            o[u] = sigmoidf_(si*s_wi[u] + pi*s_wi[8+u] + pp*s_wi[16+u]);
        #pragma unroll
        for(int l=0;l<5;l++){
            float a[8];
            float4 bb0 = ((const float4*)(s_bb + l*8))[0];
            float4 bb1 = ((const float4*)(s_bb + l*8))[1];
            a[0]=bb0.x; a[1]=bb0.y; a[2]=bb0.z; a[3]=bb0.w;
            a[4]=bb1.x; a[5]=bb1.y; a[6]=bb1.z; a[7]=bb1.w;
            #pragma unroll
            for(int v=0;v<8;v++){
                const float4* wrow = (const float4*)(s_w + (l*8+v)*8);
                float4 w0 = wrow[0], w1 = wrow[1];
                float ov = o[v];
                a[0]=fmaf(ov,w0.x,a[0]); a[1]=fmaf(ov,w0.y,a[1]);
                a[2]=fmaf(ov,w0.z,a[2]); a[3]=fmaf(ov,w0.w,a[3]);
                a[4]=fmaf(ov,w1.x,a[4]); a[5]=fmaf(ov,w1.y,a[5]);
                a[6]=fmaf(ov,w1.z,a[6]); a[7]=fmaf(ov,w1.w,a[7]);
            }
            #pragma unroll
            for(int u=0;u<8;u++) o[u]=sigmoidf_(a[u]);
        }
        float4 wo0 = ((const float4*)s_wo)[0];
        float4 wo1 = ((const float4*)s_wo)[1];
        float acc = bo_out;
        acc = fmaf(o[0],wo0.x,acc); acc = fmaf(o[1],wo0.y,acc);
        acc = fmaf(o[2],wo0.z,acc); acc = fmaf(o[3],wo0.w,acc);
        acc = fmaf(o[4],wo1.x,acc); acc = fmaf(o[5],wo1.y,acc);
        acc = fmaf(o[6],wo1.z,acc); acc = fmaf(o[7],wo1.w,acc);
        eb += -Desi*sigmoidf_(acc);             // all bonds, duplicates included

        // per-atom scatter, owned (unique) pairs only — LDS atomics
        if(table[i*NATOMS + j] == (unsigned)k){
            float bop = si+pi+pp, dpi = pi+pp;
            atomicAdd(&sAcc[i],            bop); atomicAdd(&sAcc[j],            bop);
            atomicAdd(&sAcc[NATOMS+i],     dpi); atomicAdd(&sAcc[NATOMS+j],     dpi);
            atomicAdd(&sAcc[2*NATOMS+i],   si ); atomicAdd(&sAcc[2*NATOMS+j],   si );
        }
    }
    __syncthreads();

    // non-atomic partial dump (6 KB, coalesced)
    float* pb = part + ((size_t)c*BATCH + b)*(3*NATOMS);
    for(int t=tid;t<3*NATOMS;t+=BBLK) pb[t] = sAcc[t];

    // ebond: one atomic per wave
    #pragma unroll
    for(int off=32;off>0;off>>=1) eb += __shfl_down(eb, off, 64);
    if((tid & 63)==0) atomicAdd(&out[b], eb);
}

// grid (2, BATCH), 256 threads: one atom each. Sum CH partials, atom formula.
__global__ __launch_bounds__(256) void atom_kernel(
    const float* __restrict__ sp_p, const float* __restrict__ gp, const int* __restrict__ spec,
    const float* __restrict__ part,
    float* __restrict__ out)
{
    int n = blockIdx.x*256 + threadIdx.x;
    int b = blockIdx.y;

    float D = 0.f, Dpi = 0.f, so = 0.f;
    #pragma unroll
    for(int c=0;c<CH;c++){
        const float* pb = part + ((size_t)c*BATCH + b)*(3*NATOMS);
        D   += pb[n];
        Dpi += pb[NATOMS + n];
        so  += pb[2*NATOMS + n];
    }

    float lp1=gp[0], ovun3=gp[1], ovun4=gp[2], ovun6=gp[3], ovun7=gp[4], ovun8=gp[5];
    int s = spec[n];
    float val  = sp_p[s*5+0], vale = sp_p[s*5+1], lp2 = sp_p[s*5+2];
    float ovun2= sp_p[s*5+3], ovun5= sp_p[s*5+4];

    float Nlp = 0.5f*(vale-val);
    float de  = 0.5f*(D-vale);
    float De  = fminf(ceilf(de), 0.f);          // -relu(-ceil(x)) == min(ceil(x),0)
    float t   = 1.f + de - De;
    float nlp = -De + __expf(-lp1*4.f*t*t);
    float Dlp = fmaxf(Nlp - nlp + 1.f, 0.f) - 1.f;
    float Elone = lp2*Dlp/(1.f+__expf(-75.f*Dlp));
    float dlp = D - val - Dlp/(1.f + ovun3*__expf(ovun4*Dpi));
    float denom = dlp + val;
    float otrm1 = 1.f/((denom!=0.f)?denom:1e-8f);
    float Eover = so*otrm1*dlp*sigmoidf_(-ovun2*dlp);
    float Eunder = -ovun5*(1.f-__expf(ovun6*dlp))*sigmoidf_(ovun2*dlp)
                   /(1.f + ovun7*__expf(ovun8*Dpi));

    float e = Elone + Eover + Eunder;
    #pragma unroll
    for(int off=32;off>0;off>>=1) e += __shfl_down(e, off, 64);
    if((threadIdx.x & 63)==0) atomicAdd(&out[b], e);
}

extern "C" void kernel_launch(void* const* d_in, const int* in_sizes, int n_in,
                              void* d_out, int out_size, void* d_ws, size_t ws_size,
                              hipStream_t stream)
{
    const float* x     = (const float*)d_in[0];
    const float* cell  = (const float*)d_in[1];
    const float* rcell = (const float*)d_in[2];
    const float* sp_p  = (const float*)d_in[3];
    const float* gp    = (const float*)d_in[4];
    const float* bp    = (const float*)d_in[5];
    const float* fe_wi = (const float*)d_in[6];
    const float* fe_w  = (const float*)d_in[7];
    const float* fe_b  = (const float*)d_in[8];
    const float* fe_wo = (const float*)d_in[9];
    const float* fe_bo = (const float*)d_in[10];
    const int*   bdid  = (const int*)d_in[11];
    const int*   spec  = (const int*)d_in[12];
    float* out = (float*)d_out;

    // ws: claim table (1 MiB) | partials (CH*BATCH*1536 floats)
    unsigned* table = (unsigned*)d_ws;
    float*    part  = (float*)(table + NATOMS*NATOMS);

    setup_kernel<<<1, 1024, 0, stream>>>(bdid, table, out);
    bond_kernel <<<dim3(CH, BATCH), BBLK, 0, stream>>>(
        x, cell, rcell, gp, bp, fe_wi, fe_w, fe_b, fe_wo, fe_bo, bdid, table, part, out);
    atom_kernel <<<dim3(NATOMS/256, BATCH), 256, 0, stream>>>(sp_p, gp, spec, part, out);
}

// Round 6
// 158.241 us; speedup vs baseline: 3.3884x; 1.1873x over previous
//
#include <hip/hip_runtime.h>

#define BATCH 50
#define NATOMS 512
#define NBONDS 4096
#define CH 16                   // bond chunks per batch
#define BBLK 256                // bonds per block == block size (1 bond/thread)

__device__ __forceinline__ float sigmoidf_(float x){ return 1.f/(1.f+__expf(-x)); }

// exact transcription of reference _taper
__device__ __forceinline__ float taperf_(float r, float rmin, float rmax){
    float r3  = (r > rmax) ? 1.f : 0.f;
    bool  ok  = (r <= rmax) && (r > rmin);
    float r2  = ok ? r   : 0.f;
    float r20 = ok ? 1.f : 0.f;
    float d   = rmin - rmax;
    float rterm = 1.f/(d*d*d);
    float rm  = rmin*r20;
    float rd  = rm - r2;
    float trm1 = rm + 2.f*r2 - 3.f*rmax*r20;
    return rterm*rd*rd*trm1 + r3;
}

// Single block: init used table entries, claim (lowest bond idx wins), then
// bake per-bond ownership bytes. Single-block => __syncthreads orders phases.
__global__ __launch_bounds__(1024) void setup_kernel(const int* __restrict__ bdid,
                                                     unsigned* __restrict__ table,
                                                     unsigned char* __restrict__ owned,
                                                     float* __restrict__ out){
    int tid = threadIdx.x;
    if(tid < BATCH) out[tid] = 0.f;
    for(int t=tid;t<NBONDS;t+=1024){
        int i = bdid[2*t], j = bdid[2*t+1];
        table[i*NATOMS + j] = 0xFFFFFFFFu;
    }
    __syncthreads();
    for(int t=tid;t<NBONDS;t+=1024){
        int i = bdid[2*t], j = bdid[2*t+1];
        atomicMin(&table[i*NATOMS + j], (unsigned)t);
    }
    __syncthreads();
    for(int t=tid;t<NBONDS;t+=1024){
        int i = bdid[2*t], j = bdid[2*t+1];
        owned[t] = (table[i*NATOMS + j] == (unsigned)t) ? 1 : 0;
    }
}

// grid (CH, BATCH), 256 threads, EXACTLY 1 bond/thread (R1's proven 204-VGPR
// no-spill shape). DO NOT add a min-waves arg to __launch_bounds__ and DO NOT
// loop over multiple bonds per thread: R3 (64 VGPR), R4 (128), R5 (256+spill,
// 2-bond unroll) all spilled ~1 KB/bond to scratch => 100-450 µs.
__global__ __launch_bounds__(BBLK) void bond_kernel(
    const float* __restrict__ x, const float* __restrict__ cell, const float* __restrict__ rcell,
    const float* __restrict__ gp, const float* __restrict__ bp,
    const float* __restrict__ fe_wi, const float* __restrict__ fe_w, const float* __restrict__ fe_b,
    const float* __restrict__ fe_wo, const float* __restrict__ fe_bo,
    const int* __restrict__ bdid, const unsigned char* __restrict__ owned,
    float* __restrict__ part,      // [CH][BATCH][3*NATOMS]
    float* __restrict__ out)
{
    __shared__ float sx[NATOMS*3];
    __shared__ float sAcc[3*NATOMS];            // D | Dpi | SO
    __shared__ __align__(16) float s_wi[24];
    __shared__ __align__(16) float s_w[320];
    __shared__ __align__(16) float s_bb[40];
    __shared__ __align__(16) float s_wo[8];

    int tid = threadIdx.x;
    int c   = blockIdx.x;
    int b   = blockIdx.y;

    for(int t=tid;t<NATOMS*3;t+=BBLK){ sx[t]=x[(size_t)b*NATOMS*3 + t]; sAcc[t]=0.f; }
    for(int t=tid;t<24;t+=BBLK)  s_wi[t]=fe_wi[t];
    for(int t=tid;t<320;t+=BBLK) s_w[t]=fe_w[t];
    for(int t=tid;t<40;t+=BBLK)  s_bb[t]=fe_b[t];
    for(int t=tid;t<8;t+=BBLK)   s_wo[t]=fe_wo[t];

    float c0=cell[b*9+0],c1=cell[b*9+1],c2=cell[b*9+2],
          c3=cell[b*9+3],c4=cell[b*9+4],c5=cell[b*9+5],
          c6=cell[b*9+6],c7=cell[b*9+7],c8=cell[b*9+8];
    float rc0=rcell[b*9+0],rc1=rcell[b*9+1],rc2=rcell[b*9+2],
          rc3=rcell[b*9+3],rc4=rcell[b*9+4],rc5=rcell[b*9+5],
          rc6=rcell[b*9+6],rc7=rcell[b*9+7],rc8=rcell[b*9+8];

    float botol = gp[6];
    float rosi=bp[0], ropi=bp[1], ropp=bp[2];
    float bo1=bp[3], bo2=bp[4], bo3=bp[5], bo4=bp[6], bo5=bp[7], bo6=bp[8], Desi=bp[9];
    float bo_out = fe_bo[0];
    float tmax = 2.f*botol;

    int k = c*BBLK + tid;                       // one bond per thread
    int i = bdid[2*k], j = bdid[2*k+1];
    unsigned char own = owned[k];

    __syncthreads();

    float dx0 = sx[3*i+0]-sx[3*j+0];
    float dx1 = sx[3*i+1]-sx[3*j+1];
    float dx2 = sx[3*i+2]-sx[3*j+2];
    float f0 = dx0*rc0+dx1*rc3+dx2*rc6;
    float f1 = dx0*rc1+dx1*rc4+dx2*rc7;
    float f2 = dx0*rc2+dx1*rc5+dx2*rc8;
    f0 = (f0>0.5f)?f0-1.f:f0; f0 = (f0<-0.5f)?f0+1.f:f0;
    f1 = (f1>0.5f)?f1-1.f:f1; f1 = (f1<-0.5f)?f1+1.f:f1;
    f2 = (f2>0.5f)?f2-1.f:f2; f2 = (f2<-0.5f)?f2+1.f:f2;
    float v0 = f0*c0+f1*c3+f2*c6;
    float v1 = f0*c1+f1*c4+f2*c7;
    float v2 = f0*c2+f1*c5+f2*c8;
    float r = sqrtf(v0*v0+v1*v1+v2*v2);

    float eterm1 = (1.f+botol)*__expf(bo1*__powf(r/rosi, bo2));
    float eterm2 = __expf(bo3*__powf(r/ropi, bo4));
    float eterm3 = __expf(bo5*__powf(r/ropp, bo6));
    float si = taperf_(eterm1, botol, tmax)*(eterm1-botol);
    float pi = taperf_(eterm2, botol, tmax)*eterm2;
    float pp = taperf_(eterm3, botol, tmax)*eterm3;

    // MLP: 3 -> 8 -> (8x8)x5 -> 1, sigmoid everywhere
    float o[8];
    #pragma unroll
    for(int u=0;u<8;u++)
        o[u] = sigmoidf_(si*s_wi[u] + pi*s_wi[8+u] + pp*s_wi[16+u]);
    #pragma unroll
    for(int l=0;l<5;l++){
        float a[8];
        float4 bb0 = ((const float4*)(s_bb + l*8))[0];
        float4 bb1 = ((const float4*)(s_bb + l*8))[1];
        a[0]=bb0.x; a[1]=bb0.y; a[2]=bb0.z; a[3]=bb0.w;
        a[4]=bb1.x; a[5]=bb1.y; a[6]=bb1.z; a[7]=bb1.w;
        #pragma unroll
        for(int v=0;v<8;v++){
            const float4* wrow = (const float4*)(s_w + (l*8+v)*8);
            float4 w0 = wrow[0], w1 = wrow[1];
            float ov = o[v];
            a[0]=fmaf(ov,w0.x,a[0]); a[1]=fmaf(ov,w0.y,a[1]);
            a[2]=fmaf(ov,w0.z,a[2]); a[3]=fmaf(ov,w0.w,a[3]);
            a[4]=fmaf(ov,w1.x,a[4]); a[5]=fmaf(ov,w1.y,a[5]);
            a[6]=fmaf(ov,w1.z,a[6]); a[7]=fmaf(ov,w1.w,a[7]);
        }
        #pragma unroll
        for(int u=0;u<8;u++) o[u]=sigmoidf_(a[u]);
    }
    float4 wo0 = ((const float4*)s_wo)[0];
    float4 wo1 = ((const float4*)s_wo)[1];
    float acc = bo_out;
    acc = fmaf(o[0],wo0.x,acc); acc = fmaf(o[1],wo0.y,acc);
    acc = fmaf(o[2],wo0.z,acc); acc = fmaf(o[3],wo0.w,acc);
    acc = fmaf(o[4],wo1.x,acc); acc = fmaf(o[5],wo1.y,acc);
    acc = fmaf(o[6],wo1.z,acc); acc = fmaf(o[7],wo1.w,acc);
    float eb = -Desi*sigmoidf_(acc);            // all bonds, duplicates included

    // per-atom scatter, owned (unique) pairs only — LDS atomics
    if(own){
        float bop = si+pi+pp, dpi = pi+pp;
        atomicAdd(&sAcc[i],          bop); atomicAdd(&sAcc[j],          bop);
        atomicAdd(&sAcc[NATOMS+i],   dpi); atomicAdd(&sAcc[NATOMS+j],   dpi);
        atomicAdd(&sAcc[2*NATOMS+i], si ); atomicAdd(&sAcc[2*NATOMS+j], si );
    }
    __syncthreads();

    // non-atomic partial dump (6 KB, coalesced)
    float* pb = part + ((size_t)c*BATCH + b)*(3*NATOMS);
    for(int t=tid;t<3*NATOMS;t+=BBLK) pb[t] = sAcc[t];

    // ebond: one atomic per wave
    #pragma unroll
    for(int off=32;off>0;off>>=1) eb += __shfl_down(eb, off, 64);
    if((tid & 63)==0) atomicAdd(&out[b], eb);
}

// grid (2, BATCH), 256 threads: one atom each. Sum CH partials, atom formula.
__global__ __launch_bounds__(256) void atom_kernel(
    const float* __restrict__ sp_p, const float* __restrict__ gp, const int* __restrict__ spec,
    const float* __restrict__ part,
    float* __restrict__ out)
{
    int n = blockIdx.x*256 + threadIdx.x;
    int b = blockIdx.y;

    float D = 0.f, Dpi = 0.f, so = 0.f;
    #pragma unroll
    for(int c=0;c<CH;c++){
        const float* pb = part + ((size_t)c*BATCH + b)*(3*NATOMS);
        D   += pb[n];
        Dpi += pb[NATOMS + n];
        so  += pb[2*NATOMS + n];
    }

    float lp1=gp[0], ovun3=gp[1], ovun4=gp[2], ovun6=gp[3], ovun7=gp[4], ovun8=gp[5];
    int s = spec[n];
    float val  = sp_p[s*5+0], vale = sp_p[s*5+1], lp2 = sp_p[s*5+2];
    float ovun2= sp_p[s*5+3], ovun5= sp_p[s*5+4];

    float Nlp = 0.5f*(vale-val);
    float de  = 0.5f*(D-vale);
    float De  = fminf(ceilf(de), 0.f);          // -relu(-ceil(x)) == min(ceil(x),0)
    float t   = 1.f + de - De;
    float nlp = -De + __expf(-lp1*4.f*t*t);
    float Dlp = fmaxf(Nlp - nlp + 1.f, 0.f) - 1.f;
    float Elone = lp2*Dlp/(1.f+__expf(-75.f*Dlp));
    float dlp = D - val - Dlp/(1.f + ovun3*__expf(ovun4*Dpi));
    float denom = dlp + val;
    float otrm1 = 1.f/((denom!=0.f)?denom:1e-8f);
    float Eover = so*otrm1*dlp*sigmoidf_(-ovun2*dlp);
    float Eunder = -ovun5*(1.f-__expf(ovun6*dlp))*sigmoidf_(ovun2*dlp)
                   /(1.f + ovun7*__expf(ovun8*Dpi));

    float e = Elone + Eover + Eunder;
    #pragma unroll
    for(int off=32;off>0;off>>=1) e += __shfl_down(e, off, 64);
    if((threadIdx.x & 63)==0) atomicAdd(&out[b], e);
}

extern "C" void kernel_launch(void* const* d_in, const int* in_sizes, int n_in,
                              void* d_out, int out_size, void* d_ws, size_t ws_size,
                              hipStream_t stream)
{
    const float* x     = (const float*)d_in[0];
    const float* cell  = (const float*)d_in[1];
    const float* rcell = (const float*)d_in[2];
    const float* sp_p  = (const float*)d_in[3];
    const float* gp    = (const float*)d_in[4];
    const float* bp    = (const float*)d_in[5];
    const float* fe_wi = (const float*)d_in[6];
    const float* fe_w  = (const float*)d_in[7];
    const float* fe_b  = (const float*)d_in[8];
    const float* fe_wo = (const float*)d_in[9];
    const float* fe_bo = (const float*)d_in[10];
    const int*   bdid  = (const int*)d_in[11];
    const int*   spec  = (const int*)d_in[12];
    float* out = (float*)d_out;

    // ws: claim table (1 MiB) | owned bytes (4 KiB) | partials (CH*BATCH*1536 f32)
    unsigned*      table = (unsigned*)d_ws;
    unsigned char* owned = (unsigned char*)(table + NATOMS*NATOMS);
    float*         part  = (float*)(owned + NBONDS);

    setup_kernel<<<1, 1024, 0, stream>>>(bdid, table, owned, out);
    bond_kernel <<<dim3(CH, BATCH), BBLK, 0, stream>>>(
        x, cell, rcell, gp, bp, fe_wi, fe_w, fe_b, fe_wo, fe_bo, bdid, owned, part, out);
    atom_kernel <<<dim3(NATOMS/256, BATCH), 256, 0, stream>>>(sp_p, gp, spec, part, out);
}